// Round 7
// baseline (310.452 us; speedup 1.0000x reference)
//
#include <hip/hip_runtime.h>
#include <cmath>

using f16   = _Float16;
using f16x2 = __attribute__((ext_vector_type(2))) _Float16;
using f16x4 = __attribute__((ext_vector_type(4))) _Float16;
using f16x8 = __attribute__((ext_vector_type(8))) _Float16;
using f32x4 = __attribute__((ext_vector_type(4))) float;

#define DEV __device__ __forceinline__

// ---- constants ----
constexpr int Bb  = 8;
constexpr int Nn  = 1024;
constexpr int DIM = 1024;
constexpr int Hh  = 16;
constexpr int DH  = 64;
constexpr int EQKV = 3072;   // q(1024) | k(1024) | v(1024)

DEV void async16(const f16* g, f16* l) {
  __builtin_amdgcn_global_load_lds(
      (const __attribute__((address_space(1))) void*)g,
      (__attribute__((address_space(3))) void*)l, 16, 0, 0);
}

DEV float softplusf(float x) {
  return fmaxf(x, 0.f) + __logf(1.f + __expf(-fabsf(x)));
}

// ---------------- fused 3-way transpose + fp32->fp16 convert ----------------
__global__ __launch_bounds__(256) void transpose_cvt3(const float* __restrict__ s0,
                                                      const float* __restrict__ s1,
                                                      const float* __restrict__ s2,
                                                      f16* __restrict__ d0,
                                                      f16* __restrict__ d2) {
  __shared__ float tile[32][33];
  const float* src; f16* dst; int cols;
  int bz = blockIdx.z;
  if (bz == 0)      { src = s0; dst = d0;                        cols = 2048; }
  else if (bz == 1) { src = s1; dst = d0 + (size_t)2048 * 1024;  cols = 1024; }
  else              { src = s2; dst = d2;                        cols = 1024; }
  int c0 = blockIdx.x * 32, r0 = blockIdx.y * 32;
  if (c0 >= cols) return;
  int t = threadIdx.x, tx = t & 31, ty = t >> 5;
#pragma unroll
  for (int j = 0; j < 32; j += 8)
    tile[ty + j][tx] = src[(size_t)(r0 + ty + j) * cols + c0 + tx];
  __syncthreads();
#pragma unroll
  for (int j = 0; j < 32; j += 8)
    dst[(size_t)(c0 + ty + j) * 1024 + r0 + tx] = (f16)tile[tx][ty + j];
}

// ---------------- LayerNorm (fp32 in, fp16 out) ----------------
__global__ __launch_bounds__(256) void ln_kernel(const float* __restrict__ x,
                                                 const float* __restrict__ gamma,
                                                 const float* __restrict__ beta,
                                                 f16* __restrict__ xn) {
  int row = blockIdx.x;
  int t = threadIdx.x;
  const float4* xr = (const float4*)(x + (size_t)row * DIM);
  float4 v = xr[t];
  float s  = v.x + v.y + v.z + v.w;
  float s2 = v.x * v.x + v.y * v.y + v.z * v.z + v.w * v.w;
#pragma unroll
  for (int off = 32; off; off >>= 1) {
    s  += __shfl_xor(s,  off, 64);
    s2 += __shfl_xor(s2, off, 64);
  }
  __shared__ float red[8];
  int wv = t >> 6, lane = t & 63;
  if (lane == 0) { red[wv] = s; red[4 + wv] = s2; }
  __syncthreads();
  s  = red[0] + red[1] + red[2] + red[3];
  s2 = red[4] + red[5] + red[6] + red[7];
  float mu  = s * (1.f / DIM);
  float var = s2 * (1.f / DIM) - mu * mu;
  float rs  = rsqrtf(var + 1e-5f);
  float4 g = ((const float4*)gamma)[t];
  float4 bb = ((const float4*)beta)[t];
  f16x4 o;
  o[0] = (f16)((v.x - mu) * rs * g.x + bb.x);
  o[1] = (f16)((v.y - mu) * rs * g.y + bb.y);
  o[2] = (f16)((v.z - mu) * rs * g.z + bb.z);
  o[3] = (f16)((v.w - mu) * rs * g.w + bb.w);
  ((f16x4*)(xn + (size_t)row * DIM))[t] = o;
}

// ---------------- m97-style GEMM (kept for out-proj): C[M,E] = A[M,K]*Bt[E,K]^T ----
template <bool FP32OUT>
__global__ __launch_bounds__(256) void gemm_bt(const f16* __restrict__ A,
                                               const f16* __restrict__ Bt,
                                               void* __restrict__ Cv,
                                               const float* __restrict__ bias,
                                               int M, int K, int E) {
  __shared__ f16 lA[128 * 32];
  __shared__ f16 lB[128 * 32];
  int tid  = threadIdx.x;
  int lane = tid & 63;
  int wv   = __builtin_amdgcn_readfirstlane(tid >> 6);
  int nbe  = E >> 7;
  int bm = blockIdx.x / nbe, be = blockIdx.x % nbe;
  size_t m0 = (size_t)bm * 128, e0 = (size_t)be * 128;
  int wm = (wv & 1) * 64, we = (wv >> 1) * 64;
  int lm = lane & 15, q = lane >> 4;

  f32x4 acc[4][4] = {};

  int row_s[2], cg_s[2];
#pragma unroll
  for (int r = 0; r < 2; ++r) {
    int s = r * 256 + tid;
    row_s[r] = s >> 2;
    cg_s[r]  = (s & 3) ^ ((row_s[r] >> 1) & 3);
  }
  const f16* pa[4];
  const f16* pb[4];
#pragma unroll
  for (int i = 0; i < 4; ++i) {
    int ra = wm + i * 16 + lm;
    pa[i] = lA + ra * 32 + (q ^ ((ra >> 1) & 3)) * 8;
    int rb = we + i * 16 + lm;
    pb[i] = lB + rb * 32 + (q ^ ((rb >> 1) & 3)) * 8;
  }

  for (int k0 = 0; k0 < K; k0 += 32) {
#pragma unroll
    for (int r = 0; r < 2; ++r) {
      const f16* ga = A  + (m0 + row_s[r]) * K + k0 + cg_s[r] * 8;
      const f16* gb = Bt + (e0 + row_s[r]) * K + k0 + cg_s[r] * 8;
      async16(ga, lA + (r * 256 + wv * 64) * 8);
      async16(gb, lB + (r * 256 + wv * 64) * 8);
    }
    __syncthreads();
    f16x8 af[4], bf[4];
#pragma unroll
    for (int i = 0; i < 4; ++i) {
      af[i] = *(const f16x8*)pa[i];
      bf[i] = *(const f16x8*)pb[i];
    }
#pragma unroll
    for (int i = 0; i < 4; ++i)
#pragma unroll
      for (int j = 0; j < 4; ++j)
        acc[i][j] = __builtin_amdgcn_mfma_f32_16x16x32_f16(af[i], bf[j], acc[i][j], 0, 0, 0);
    __syncthreads();
  }

#pragma unroll
  for (int i = 0; i < 4; ++i) {
    size_t mbase = m0 + wm + i * 16 + q * 4;
#pragma unroll
    for (int j = 0; j < 4; ++j) {
      size_t e = e0 + we + j * 16 + lm;
#pragma unroll
      for (int g = 0; g < 4; ++g) {
        float val = acc[i][j][g];
        if (FP32OUT)
          ((float*)Cv)[(mbase + g) * (size_t)E + e] = val + bias[e];
        else
          ((f16*)Cv)[(mbase + g) * (size_t)E + e] = (f16)val;
      }
    }
  }
}

// ---------------- 256x256 / BK=64 / 8-wave GEMM, 4-phase fine-grained schedule ----
// Per K-tile: barrier A (closes t-1 compute -> next buffer free), issue ALL 8
// prefetch loads for t+1 (they get 4 phases ~ >1000 cy of slack), single
// vmcnt(8) (t's 8 loads arrived; t+1's 8 remain in flight), barrier E, then
// 4 phases x 16 MFMA (C-quadrants: i0-3/j0-1, i0-3/j2-3, i4-7/j0-1, i4-7/j2-3)
// with per-phase barriers to keep waves phase-locked (m196: fine interleave is
// the lever; role-split makes setprio pay).  Never vmcnt(0) in the loop.
template <bool FP32OUT>
__global__ __launch_bounds__(512, 2) void gemm256(const f16* __restrict__ A,
                                                  const f16* __restrict__ Bt,
                                                  void* __restrict__ Cv,
                                                  const float* __restrict__ bias,
                                                  int M, int K, int E) {
  __shared__ f16 sm[65536];   // 128 KiB
  const int tid  = threadIdx.x;
  const int lane = tid & 63;
  const int wv   = __builtin_amdgcn_readfirstlane(tid >> 6);   // 0..7
  const int lm   = lane & 15, q = lane >> 4;
  const int wrow = (wv >> 2) * 128;   // wave row offset in 256-tile
  const int wcol = (wv & 3) * 64;     // wave col offset

  const int nbe = E >> 8;
  const int cpx = gridDim.x >> 3;     // grid % 8 == 0 (bijective XCD swizzle)
  const int bid = blockIdx.x;
  const int swz = (bid & 7) * cpx + (bid >> 3);
  const int bm = swz / nbe, be = swz % nbe;
  const size_t m0 = (size_t)bm * 256, e0 = (size_t)be * 256;

  const int rl  = lane >> 3;          // row within wave-group
  const int pcp = lane & 7;           // phys chunk
  const int cg  = pcp ^ rl;           // logical (source) chunk = pc ^ (row&7)
  const f16* aS = A  + (m0 + (size_t)(wv * 8 + rl)) * K + cg * 8;
  const f16* bS = Bt + (e0 + (size_t)((wv >> 2) * 64 + (wv & 3) * 8 + rl)) * K + cg * 8;
  const int aDofs = wv * 512;                                     // halfs
  const int bDofs = 16384 + ((wv >> 2) * 64 + (wv & 3) * 8) * 64; // halfs

  const int x0 = ((0 + q) ^ (lm & 7)) * 8;
  const int x1 = ((4 + q) ^ (lm & 7)) * 8;

  const int NT = K >> 6;

  // ---- prologue: tile 0 -> buffer 0 (8 loads/thread) ----
  async16(aS,                     sm + aDofs);
  async16(aS + (size_t)64 * K,    sm + aDofs + 64 * 64);
  async16(aS + (size_t)128 * K,   sm + aDofs + 128 * 64);
  async16(aS + (size_t)192 * K,   sm + aDofs + 192 * 64);
  async16(bS,                     sm + bDofs);
  async16(bS + (size_t)32 * K,    sm + bDofs + 32 * 64);
  async16(bS + (size_t)128 * K,   sm + bDofs + 128 * 64);
  async16(bS + (size_t)160 * K,   sm + bDofs + 160 * 64);

  f32x4 acc[8][4] = {};
  f16x8 af[4][2], bf[4][2];

  for (int t = 0; t < NT; ++t) {
    const int b = t & 1, nb = b ^ 1;
    const int tn = (t + 1 < NT) ? t + 1 : t;   // clamp: uniform vmcnt counts
    const f16* pA = sm + b * 32768;
    const f16* pB = pA + 16384;
    f16* aD = sm + nb * 32768 + aDofs;
    f16* bD = sm + nb * 32768 + bDofs;
    const f16* aSk = aS + tn * 64;
    const f16* bSk = bS + tn * 64;

    __builtin_amdgcn_s_barrier();   // A: t-1 compute closed -> buffer nb free

    // ---- issue ALL 8 prefetch loads for t+1 (4 phases of slack) ----
    async16(aSk,                   aD);
    async16(aSk + (size_t)64 * K,  aD + 64 * 64);
    async16(aSk + (size_t)128 * K, aD + 128 * 64);
    async16(aSk + (size_t)192 * K, aD + 192 * 64);
    async16(bSk,                   bD);
    async16(bSk + (size_t)32 * K,  bD + 32 * 64);
    async16(bSk + (size_t)128 * K, bD + 128 * 64);
    async16(bSk + (size_t)160 * K, bD + 160 * 64);

    asm volatile("s_waitcnt vmcnt(8)" ::: "memory");  // tile t's 8 arrived
    __builtin_amdgcn_s_barrier();   // E: tile t visible to all waves

    // ---- phase 1: (i0-3, j0-1) ----
#pragma unroll
    for (int i = 0; i < 4; ++i) {
      const f16* p = pA + (wrow + i * 16 + lm) * 64;
      af[i][0] = *(const f16x8*)(p + x0);
      af[i][1] = *(const f16x8*)(p + x1);
    }
#pragma unroll
    for (int j = 0; j < 2; ++j) {
      const f16* p = pB + (wcol + j * 16 + lm) * 64;
      bf[j][0] = *(const f16x8*)(p + x0);
      bf[j][1] = *(const f16x8*)(p + x1);
    }
    __builtin_amdgcn_s_setprio(1);
#pragma unroll
    for (int i = 0; i < 4; ++i)
#pragma unroll
      for (int j = 0; j < 2; ++j) {
        acc[i][j] = __builtin_amdgcn_mfma_f32_16x16x32_f16(af[i][0], bf[j][0], acc[i][j], 0, 0, 0);
        acc[i][j] = __builtin_amdgcn_mfma_f32_16x16x32_f16(af[i][1], bf[j][1], acc[i][j], 0, 0, 0);
      }
    __builtin_amdgcn_s_setprio(0);
    __builtin_amdgcn_s_barrier();

    // ---- phase 2: (i0-3, j2-3) ----
#pragma unroll
    for (int j = 0; j < 2; ++j) {
      const f16* p = pB + (wcol + 32 + j * 16 + lm) * 64;
      bf[2 + j][0] = *(const f16x8*)(p + x0);
      bf[2 + j][1] = *(const f16x8*)(p + x1);
    }
    __builtin_amdgcn_s_setprio(1);
#pragma unroll
    for (int i = 0; i < 4; ++i)
#pragma unroll
      for (int j = 2; j < 4; ++j) {
        acc[i][j] = __builtin_amdgcn_mfma_f32_16x16x32_f16(af[i][0], bf[j][0], acc[i][j], 0, 0, 0);
        acc[i][j] = __builtin_amdgcn_mfma_f32_16x16x32_f16(af[i][1], bf[j][1], acc[i][j], 0, 0, 0);
      }
    __builtin_amdgcn_s_setprio(0);
    __builtin_amdgcn_s_barrier();

    // ---- phase 3: (i4-7, j0-1) ----
#pragma unroll
    for (int i = 0; i < 4; ++i) {
      const f16* p = pA + (wrow + 64 + i * 16 + lm) * 64;
      af[i][0] = *(const f16x8*)(p + x0);
      af[i][1] = *(const f16x8*)(p + x1);
    }
    __builtin_amdgcn_s_setprio(1);
#pragma unroll
    for (int i = 0; i < 4; ++i)
#pragma unroll
      for (int j = 0; j < 2; ++j) {
        acc[4 + i][j] = __builtin_amdgcn_mfma_f32_16x16x32_f16(af[i][0], bf[j][0], acc[4 + i][j], 0, 0, 0);
        acc[4 + i][j] = __builtin_amdgcn_mfma_f32_16x16x32_f16(af[i][1], bf[j][1], acc[4 + i][j], 0, 0, 0);
      }
    __builtin_amdgcn_s_setprio(0);
    __builtin_amdgcn_s_barrier();

    // ---- phase 4: (i4-7, j2-3) ----
    __builtin_amdgcn_s_setprio(1);
#pragma unroll
    for (int i = 0; i < 4; ++i)
#pragma unroll
      for (int j = 2; j < 4; ++j) {
        acc[4 + i][j] = __builtin_amdgcn_mfma_f32_16x16x32_f16(af[i][0], bf[j][0], acc[4 + i][j], 0, 0, 0);
        acc[4 + i][j] = __builtin_amdgcn_mfma_f32_16x16x32_f16(af[i][1], bf[j][1], acc[4 + i][j], 0, 0, 0);
      }
    __builtin_amdgcn_s_setprio(0);
  }
  asm volatile("s_waitcnt vmcnt(0)" ::: "memory");

  // ---- epilogue ----
#pragma unroll
  for (int ii = 0; ii < 8; ++ii) {
    size_t mrow = m0 + wrow + (ii >> 2) * 64 + (ii & 3) * 16 + q * 4;
#pragma unroll
    for (int j = 0; j < 4; ++j) {
      size_t e = e0 + wcol + j * 16 + lm;
#pragma unroll
      for (int g = 0; g < 4; ++g) {
        float val = acc[ii][j][g];
        if (FP32OUT)
          ((float*)Cv)[(mrow + g) * (size_t)E + e] = val + bias[e];
        else
          ((f16*)Cv)[(mrow + g) * (size_t)E + e] = (f16)val;
      }
    }
  }
}

// ---------------- polar precompute (pair-of-d, vectorized I/O) ----------------
__global__ __launch_bounds__(256) void polar_kernel(const f16* __restrict__ qkv,
                                                    const float* __restrict__ freqs,
                                                    const float* __restrict__ fbias,
                                                    f16* __restrict__ Qp,
                                                    f16* __restrict__ Kp,
                                                    f16* __restrict__ Vt) {
  __shared__ f16 vt[64 * 66];
  int tid = threadIdx.x;
  int bx = blockIdx.x;
  int nt = bx & 15, bh = bx >> 4;
  int b = bh >> 4, h = bh & 15;
  size_t tok0 = (size_t)b * Nn + nt * 64;
  int n0 = nt * 64;
  constexpr float kScale = 0.125f;  // DH^-0.5 folded into Q
#pragma unroll
  for (int i = 0; i < 8; ++i) {
    int e2 = tid + i * 256;
    int nl = e2 >> 5, dp = (e2 & 31) * 2;
    size_t src = (tok0 + nl) * EQKV + h * 64 + dp;
    f16x2 q2 = *(const f16x2*)(qkv + src);
    f16x2 k2 = *(const f16x2*)(qkv + src + 1024);
    f16x2 v2 = *(const f16x2*)(qkv + src + 2048);
    int fidx = (n0 + nl) * 64 + dp;
    float2 f2  = *(const float2*)(freqs + fidx);
    float2 fb2 = *(const float2*)(fbias + fidx);
    f16x2 qc, qs, kc, ksn;
#pragma unroll
    for (int u = 0; u < 2; ++u) {
      float fq = u ? f2.y : f2.x;
      float fk = fq + (u ? fb2.y : fb2.x);
      float spq = softplusf((float)q2[u]) * kScale;
      float spk = softplusf((float)k2[u]);
      float snq, csq, snk, csk;
      __sincosf(fq, &snq, &csq);
      __sincosf(fk, &snk, &csk);
      qc[u]  = (f16)(spq * csq);
      qs[u]  = (f16)(spq * snq);
      kc[u]  = (f16)(spk * csk);
      ksn[u] = (f16)(spk * snk);
    }
    size_t dst = ((size_t)bh * Nn + n0 + nl) * 128 + dp;
    *(f16x2*)(Qp + dst)      = qc;
    *(f16x2*)(Qp + dst + 64) = qs;
    *(f16x2*)(Kp + dst)      = kc;
    *(f16x2*)(Kp + dst + 64) = ksn;
    vt[dp * 66 + nl]       = v2[0];
    vt[(dp + 1) * 66 + nl] = v2[1];
  }
  __syncthreads();
#pragma unroll
  for (int i = 0; i < 16; ++i) {
    int e = tid + i * 256;
    int d = e >> 6, nl = e & 63;
    Vt[((size_t)bh * 64 + d) * Nn + n0 + nl] = vt[d * 66 + nl];
  }
}

// ---------------- flash attention v5 (round-1 exact, 76.6 us) + T5 setprio ----------------
// S^T = Kp*Qp^T (16x16x32); P feeds PV (16x16x16) straight from registers.
// 256 threads / 4 waves / 128 q-rows / 1024 blocks / 3 blocks/CU.  The ONLY
// change vs the round-1 measured source: s_setprio(1)/(0) around the two MFMA
// clusters (m191: +4-7% attn, isolated).  Rounds 2-6 showed every other
// variant (8-wave shape, counted vmcnt, exp2/defer-max/cvt_pk) regresses.
constexpr int VK0 = 0;       // halfs
constexpr int VK1 = 8192;
constexpr int VV0 = 16384;   // 80*64 = 5120 halfs per buffer
constexpr int VV1 = 21504;
constexpr int VEND = 26624;

__global__ __launch_bounds__(256, 3) void attn_kernel(const f16* __restrict__ Qp,
                                                      const f16* __restrict__ Kp,
                                                      const f16* __restrict__ Vt,
                                                      f16* __restrict__ attout) {
  __shared__ f16 smem[VEND];  // 52 KB

  int tid = threadIdx.x, lane = tid & 63;
  int wv = __builtin_amdgcn_readfirstlane(tid >> 6);  // 0..3
  int lm = lane & 15, q = lane >> 4;
  int bx = blockIdx.x;
  int bh = (bx & 7) | ((bx >> 6) << 3);  // XCD swizzle: same head -> same bx%8
  int qt = (bx >> 3) & 7;                // 8 q-tiles of 128 rows
  const f16* Kbase = Kp + (size_t)bh * Nn * 128;
  const f16* Vbase = Vt + (size_t)bh * 64 * Nn;

  // ---- init V rows 64..79 (row 64 = ones, rest 0) in BOTH buffers, once ----
  {
    int idx = tid * 4;                 // 0..1020
    f16 val = (idx < 64) ? (f16)1.0f : (f16)0.0f;  // idx>>6==0 -> row 64
    f16x4 v4 = {val, val, val, val};
    *(f16x4*)(smem + VV0 + 64 * 64 + idx) = v4;
    *(f16x4*)(smem + VV1 + 64 * 64 + idx) = v4;
  }

  // ---- prologue: DMA K/V tile 0 ----
#pragma unroll
  for (int i = 0; i < 4; ++i) {
    int s = i * 256 + tid;
    int r = s >> 4, c = s & 15;
    int g = c ^ (r & 15);
    async16(Kbase + (size_t)r * 128 + g * 8, smem + VK0 + (i * 256 + wv * 64) * 8);
  }
#pragma unroll
  for (int i = 0; i < 2; ++i) {
    int s = i * 256 + tid;
    int r = s >> 3, c = s & 7;
    int g = c ^ (r & 7);
    async16(Vbase + (size_t)r * Nn + g * 8, smem + VV0 + (i * 256 + wv * 64) * 8);
  }

  // ---- Q frags: 32 rows/wave = 2 groups of 16 (B operand of S^T) ----
  f16x8 qf[2][4];
  {
    const f16* Qb = Qp + ((size_t)bh * Nn + qt * 128 + wv * 32) * 128;
#pragma unroll
    for (int grp = 0; grp < 2; ++grp)
#pragma unroll
      for (int ks = 0; ks < 4; ++ks)
        qf[grp][ks] = *(const f16x8*)(Qb + (size_t)(grp * 16 + lm) * 128 + ks * 32 + q * 8);
  }

  f32x4 O[2][5] = {};   // O^T per group; [.][4] row 0 = softmax denominator
  float mrow[2] = {-INFINITY, -INFINITY};

  for (int kt = 0; kt < 16; ++kt) {
    __syncthreads();  // tile kt ready (its DMA was issued a full compute-phase ago)

    if (kt < 15) {
      f16* nK = smem + ((kt & 1) ? VK0 : VK1);
      f16* nV = smem + ((kt & 1) ? VV0 : VV1);
#pragma unroll
      for (int i = 0; i < 4; ++i) {
        int s = i * 256 + tid;
        int r = s >> 4, c = s & 15;
        int g = c ^ (r & 15);
        async16(Kbase + (size_t)((kt + 1) * 64 + r) * 128 + g * 8, nK + (i * 256 + wv * 64) * 8);
      }
#pragma unroll
      for (int i = 0; i < 2; ++i) {
        int s = i * 256 + tid;
        int r = s >> 3, c = s & 7;
        int g = c ^ (r & 7);
        async16(Vbase + (size_t)r * Nn + (kt + 1) * 64 + g * 8, nV + (i * 256 + wv * 64) * 8);
      }
    }
    const f16* sK = smem + ((kt & 1) ? VK1 : VK0);
    const f16* sV = smem + ((kt & 1) ? VV1 : VV0);

    // ---- S^T = Kp * Qp^T (64 keys x 32 q-rows); kf loaded once per nt ----
    f32x4 S[2][4] = {};
    __builtin_amdgcn_s_setprio(1);
#pragma unroll
    for (int nt = 0; nt < 4; ++nt) {
      f16x8 kf[4];
#pragma unroll
      for (int ks = 0; ks < 4; ++ks)
        kf[ks] = *(const f16x8*)(sK + (nt * 16 + lm) * 128 + (((ks * 4 + q) ^ lm) * 8));
#pragma unroll
      for (int ks = 0; ks < 4; ++ks) {
        S[0][nt] = __builtin_amdgcn_mfma_f32_16x16x32_f16(kf[ks], qf[0][ks], S[0][nt], 0, 0, 0);
        S[1][nt] = __builtin_amdgcn_mfma_f32_16x16x32_f16(kf[ks], qf[1][ks], S[1][nt], 0, 0, 0);
      }
    }
    __builtin_amdgcn_s_setprio(0);

    // ---- online softmax per group (no rowsum: folded into PV ones-row) ----
    f16x4 pf[2][4];
#pragma unroll
    for (int grp = 0; grp < 2; ++grp) {
      float mx = -INFINITY;
#pragma unroll
      for (int nt = 0; nt < 4; ++nt)
#pragma unroll
        for (int g = 0; g < 4; ++g) mx = fmaxf(mx, S[grp][nt][g]);
      mx = fmaxf(mx, __shfl_xor(mx, 16, 64));
      mx = fmaxf(mx, __shfl_xor(mx, 32, 64));
      float mn = fmaxf(mrow[grp], mx);
      float alpha = __expf(mrow[grp] - mn);
      mrow[grp] = mn;
#pragma unroll
      for (int nt = 0; nt < 4; ++nt)
#pragma unroll
        for (int g = 0; g < 4; ++g)
          pf[grp][nt][g] = (f16)__expf(S[grp][nt][g] - mn);
#pragma unroll
      for (int nto = 0; nto < 5; ++nto)
#pragma unroll
        for (int g = 0; g < 4; ++g) O[grp][nto][g] *= alpha;
    }

    // ---- O^T += V^T * P^T ; vf loaded once per (nto,nt), reused by both groups ----
    __builtin_amdgcn_s_setprio(1);
#pragma unroll
    for (int nto = 0; nto < 5; ++nto) {
      int r = nto * 16 + lm;
#pragma unroll
      for (int nt = 0; nt < 4; ++nt) {
        int c16 = (nt * 2 + (q >> 1)) ^ (r & 7);
        f16x4 vf = *(const f16x4*)(sV + r * 64 + c16 * 8 + (q & 1) * 4);
        O[0][nto] = __builtin_amdgcn_mfma_f32_16x16x16f16(vf, pf[0][nt], O[0][nto], 0, 0, 0);
        O[1][nto] = __builtin_amdgcn_mfma_f32_16x16x16f16(vf, pf[1][nt], O[1][nto], 0, 0, 0);
      }
    }
    __builtin_amdgcn_s_setprio(0);
  }

  // ---- epilogue: l = O[grp][4][0] (d-row 64, lives in q==0 lanes), broadcast ----
  int b = bh >> 4, h = bh & 15;
#pragma unroll
  for (int grp = 0; grp < 2; ++grp) {
    float l = __shfl(O[grp][4][0], lm, 64);  // source lane lm (q==0) holds the rowsum
    float inv = 1.f / l;
    size_t token = (size_t)b * Nn + qt * 128 + wv * 32 + grp * 16 + lm;
#pragma unroll
    for (int nto = 0; nto < 4; ++nto) {
      f16x4 o4;
#pragma unroll
      for (int g = 0; g < 4; ++g) o4[g] = (f16)(O[grp][nto][g] * inv);
      *(f16x4*)(attout + token * (size_t)(Hh * DH) + h * 64 + nto * 16 + q * 4) = o4;
    }
  }
}

// ---------------- launch ----------------
extern "C" void kernel_launch(void* const* d_in, const int* in_sizes, int n_in,
                              void* d_out, int out_size, void* d_ws, size_t ws_size,
                              hipStream_t stream) {
  const float* x     = (const float*)d_in[0];
  const float* freqs = (const float*)d_in[1];
  const float* fbias = (const float*)d_in[2];
  const float* gamma = (const float*)d_in[3];
  const float* beta  = (const float*)d_in[4];
  const float* w_qk  = (const float*)d_in[5];
  const float* w_v   = (const float*)d_in[6];
  const float* w_out = (const float*)d_in[7];
  const float* b_out = (const float*)d_in[8];
  float* out = (float*)d_out;

  const size_t T = (size_t)Bb * Nn;  // 8192 tokens
  f16* WqkvT = (f16*)d_ws;                        // [3072][1024]
  f16* WoutT = WqkvT + (size_t)EQKV * DIM;        // [1024][1024]
  f16* Xn    = WoutT + (size_t)DIM * DIM;         // [8192][1024]
  f16* QKV   = Xn + T * DIM;                      // [8192][3072]
  f16* AttO  = QKV + T * EQKV;                    // [8192][1024]
  f16* Qp    = AttO + T * DIM;                    // [128][1024][128]
  f16* Kp    = Qp + (size_t)128 * Nn * 128;       // [128][1024][128]
  f16* Vt    = Kp + (size_t)128 * Nn * 128;       // [128][64][1024]

  transpose_cvt3<<<dim3(64, 32, 3), 256, 0, stream>>>(w_qk, w_v, w_out, WqkvT, WoutT);

  ln_kernel<<<(int)T, 256, 0, stream>>>(x, gamma, beta, Xn);

  // QKV projection: 256^2 8-wave 4-phase kernel (grid 32x12 = 384, %8==0)
  gemm256<false><<<(int)(T / 256) * (EQKV / 256), 512, 0, stream>>>(
      Xn, WqkvT, (void*)QKV, nullptr, (int)T, DIM, EQKV);

  polar_kernel<<<Bb * Hh * (Nn / 64), 256, 0, stream>>>(QKV, freqs, fbias, Qp, Kp, Vt);

  // attention: v5 shell — 1024 blocks (128 bh x 8 qt) x 256 threads, 3 blocks/CU
  attn_kernel<<<Bb * Hh * (Nn / 128), 256, 0, stream>>>(Qp, Kp, Vt, AttO);

  gemm_bt<true><<<(int)(T / 128) * (DIM / 128), 256, 0, stream>>>(
      AttO, WoutT, (void*)out, b_out, (int)T, DIM, DIM);
}

// Round 8
// 295.039 us; speedup vs baseline: 1.0522x; 1.0522x over previous
//
#include <hip/hip_runtime.h>
#include <cmath>

using f16   = _Float16;
using f16x2 = __attribute__((ext_vector_type(2))) _Float16;
using f16x4 = __attribute__((ext_vector_type(4))) _Float16;
using f16x8 = __attribute__((ext_vector_type(8))) _Float16;
using f32x4 = __attribute__((ext_vector_type(4))) float;

#define DEV __device__ __forceinline__

// ---- constants ----
constexpr int Bb  = 8;
constexpr int Nn  = 1024;
constexpr int DIM = 1024;
constexpr int Hh  = 16;
constexpr int DH  = 64;
constexpr int EQKV = 3072;   // q(1024) | k(1024) | v(1024)

DEV void async16(const f16* g, f16* l) {
  __builtin_amdgcn_global_load_lds(
      (const __attribute__((address_space(1))) void*)g,
      (__attribute__((address_space(3))) void*)l, 16, 0, 0);
}

DEV float softplusf(float x) {
  return fmaxf(x, 0.f) + __logf(1.f + __expf(-fabsf(x)));
}

// ---------------- fused 3-way transpose + fp32->fp16 convert ----------------
__global__ __launch_bounds__(256) void transpose_cvt3(const float* __restrict__ s0,
                                                      const float* __restrict__ s1,
                                                      const float* __restrict__ s2,
                                                      f16* __restrict__ d0,
                                                      f16* __restrict__ d2) {
  __shared__ float tile[32][33];
  const float* src; f16* dst; int cols;
  int bz = blockIdx.z;
  if (bz == 0)      { src = s0; dst = d0;                        cols = 2048; }
  else if (bz == 1) { src = s1; dst = d0 + (size_t)2048 * 1024;  cols = 1024; }
  else              { src = s2; dst = d2;                        cols = 1024; }
  int c0 = blockIdx.x * 32, r0 = blockIdx.y * 32;
  if (c0 >= cols) return;
  int t = threadIdx.x, tx = t & 31, ty = t >> 5;
#pragma unroll
  for (int j = 0; j < 32; j += 8)
    tile[ty + j][tx] = src[(size_t)(r0 + ty + j) * cols + c0 + tx];
  __syncthreads();
#pragma unroll
  for (int j = 0; j < 32; j += 8)
    dst[(size_t)(c0 + ty + j) * 1024 + r0 + tx] = (f16)tile[tx][ty + j];
}

// ---------------- trig table: (cos f, sin f, cos(f+b), sin(f+b)) per (n,d) ----
__global__ __launch_bounds__(256) void trig_prep(const float* __restrict__ freqs,
                                                 const float* __restrict__ fbias,
                                                 float4* __restrict__ trig) {
  int i = blockIdx.x * 256 + threadIdx.x;   // 0..65535
  float f = freqs[i], fb = fbias[i];
  float cq, sq, ck, sk;
  __sincosf(f, &sq, &cq);
  __sincosf(f + fb, &sk, &ck);
  trig[i] = make_float4(cq, sq, ck, sk);
}

// ---------------- LayerNorm (fp32 in, fp16 out) ----------------
__global__ __launch_bounds__(256) void ln_kernel(const float* __restrict__ x,
                                                 const float* __restrict__ gamma,
                                                 const float* __restrict__ beta,
                                                 f16* __restrict__ xn) {
  int row = blockIdx.x;
  int t = threadIdx.x;
  const float4* xr = (const float4*)(x + (size_t)row * DIM);
  float4 v = xr[t];
  float s  = v.x + v.y + v.z + v.w;
  float s2 = v.x * v.x + v.y * v.y + v.z * v.z + v.w * v.w;
#pragma unroll
  for (int off = 32; off; off >>= 1) {
    s  += __shfl_xor(s,  off, 64);
    s2 += __shfl_xor(s2, off, 64);
  }
  __shared__ float red[8];
  int wv = t >> 6, lane = t & 63;
  if (lane == 0) { red[wv] = s; red[4 + wv] = s2; }
  __syncthreads();
  s  = red[0] + red[1] + red[2] + red[3];
  s2 = red[4] + red[5] + red[6] + red[7];
  float mu  = s * (1.f / DIM);
  float var = s2 * (1.f / DIM) - mu * mu;
  float rs  = rsqrtf(var + 1e-5f);
  float4 g = ((const float4*)gamma)[t];
  float4 bb = ((const float4*)beta)[t];
  f16x4 o;
  o[0] = (f16)((v.x - mu) * rs * g.x + bb.x);
  o[1] = (f16)((v.y - mu) * rs * g.y + bb.y);
  o[2] = (f16)((v.z - mu) * rs * g.z + bb.z);
  o[3] = (f16)((v.w - mu) * rs * g.w + bb.w);
  ((f16x4*)(xn + (size_t)row * DIM))[t] = o;
}

// ---------------- m97-style GEMM (out-proj): C[M,E] = A[M,K]*Bt[E,K]^T ----
template <bool FP32OUT>
__global__ __launch_bounds__(256) void gemm_bt(const f16* __restrict__ A,
                                               const f16* __restrict__ Bt,
                                               void* __restrict__ Cv,
                                               const float* __restrict__ bias,
                                               int M, int K, int E) {
  __shared__ f16 lA[128 * 32];
  __shared__ f16 lB[128 * 32];
  int tid  = threadIdx.x;
  int lane = tid & 63;
  int wv   = __builtin_amdgcn_readfirstlane(tid >> 6);
  int nbe  = E >> 7;
  int bm = blockIdx.x / nbe, be = blockIdx.x % nbe;
  size_t m0 = (size_t)bm * 128, e0 = (size_t)be * 128;
  int wm = (wv & 1) * 64, we = (wv >> 1) * 64;
  int lm = lane & 15, q = lane >> 4;

  f32x4 acc[4][4] = {};

  int row_s[2], cg_s[2];
#pragma unroll
  for (int r = 0; r < 2; ++r) {
    int s = r * 256 + tid;
    row_s[r] = s >> 2;
    cg_s[r]  = (s & 3) ^ ((row_s[r] >> 1) & 3);
  }
  const f16* pa[4];
  const f16* pb[4];
#pragma unroll
  for (int i = 0; i < 4; ++i) {
    int ra = wm + i * 16 + lm;
    pa[i] = lA + ra * 32 + (q ^ ((ra >> 1) & 3)) * 8;
    int rb = we + i * 16 + lm;
    pb[i] = lB + rb * 32 + (q ^ ((rb >> 1) & 3)) * 8;
  }

  for (int k0 = 0; k0 < K; k0 += 32) {
#pragma unroll
    for (int r = 0; r < 2; ++r) {
      const f16* ga = A  + (m0 + row_s[r]) * K + k0 + cg_s[r] * 8;
      const f16* gb = Bt + (e0 + row_s[r]) * K + k0 + cg_s[r] * 8;
      async16(ga, lA + (r * 256 + wv * 64) * 8);
      async16(gb, lB + (r * 256 + wv * 64) * 8);
    }
    __syncthreads();
    f16x8 af[4], bf[4];
#pragma unroll
    for (int i = 0; i < 4; ++i) {
      af[i] = *(const f16x8*)pa[i];
      bf[i] = *(const f16x8*)pb[i];
    }
#pragma unroll
    for (int i = 0; i < 4; ++i)
#pragma unroll
      for (int j = 0; j < 4; ++j)
        acc[i][j] = __builtin_amdgcn_mfma_f32_16x16x32_f16(af[i], bf[j], acc[i][j], 0, 0, 0);
    __syncthreads();
  }

#pragma unroll
  for (int i = 0; i < 4; ++i) {
    size_t mbase = m0 + wm + i * 16 + q * 4;
#pragma unroll
    for (int j = 0; j < 4; ++j) {
      size_t e = e0 + we + j * 16 + lm;
#pragma unroll
      for (int g = 0; g < 4; ++g) {
        float val = acc[i][j][g];
        if (FP32OUT)
          ((float*)Cv)[(mbase + g) * (size_t)E + e] = val + bias[e];
        else
          ((f16*)Cv)[(mbase + g) * (size_t)E + e] = (f16)val;
      }
    }
  }
}

// ---------------- 256x256 QKV GEMM + fused polar epilogue ----------------
// 4-phase fine-grained schedule (round-7).  Epilogue applies the polar
// transform directly from f32 acc:
//   q-section: sp = softplus(v)*DH^-0.5;  Qp[bh][n][2d,2d+1] = sp*(cos f, sin f)
//   k-section: sp = softplus(v);          Kp[bh][n][2d,2d+1] = sp*(cos(f+b), sin(f+b))
//   v-section: raw f16 -> Vn[token][h*64+d]  (transposed later by vtrans)
// The interleaved (cos,sin) Q/K layout is a fixed permutation of the 128-dim;
// QK^T dot products are permutation-invariant, so attn needs no change.
__global__ __launch_bounds__(512, 2) void gemm_qkv(const f16* __restrict__ A,
                                                   const f16* __restrict__ Bt,
                                                   f16* __restrict__ Qp,
                                                   f16* __restrict__ Kp,
                                                   f16* __restrict__ Vn,
                                                   const float4* __restrict__ trig,
                                                   int M, int K) {
  __shared__ f16 sm[65536];   // 128 KiB
  const int tid  = threadIdx.x;
  const int lane = tid & 63;
  const int wv   = __builtin_amdgcn_readfirstlane(tid >> 6);   // 0..7
  const int lm   = lane & 15, q = lane >> 4;
  const int wrow = (wv >> 2) * 128;
  const int wcol = (wv & 3) * 64;

  const int nbe = EQKV >> 8;          // 12
  const int cpx = gridDim.x >> 3;     // grid % 8 == 0 (bijective XCD swizzle)
  const int bid = blockIdx.x;
  const int swz = (bid & 7) * cpx + (bid >> 3);
  const int bm = swz / nbe, be = swz % nbe;
  const size_t m0 = (size_t)bm * 256, e0 = (size_t)be * 256;

  const int rl  = lane >> 3;
  const int pcp = lane & 7;
  const int cg  = pcp ^ rl;
  const f16* aS = A  + (m0 + (size_t)(wv * 8 + rl)) * K + cg * 8;
  const f16* bS = Bt + (e0 + (size_t)((wv >> 2) * 64 + (wv & 3) * 8 + rl)) * K + cg * 8;
  const int aDofs = wv * 512;
  const int bDofs = 16384 + ((wv >> 2) * 64 + (wv & 3) * 8) * 64;

  const int x0 = ((0 + q) ^ (lm & 7)) * 8;
  const int x1 = ((4 + q) ^ (lm & 7)) * 8;

  const int NT = K >> 6;

  // ---- prologue: tile 0 -> buffer 0 (8 loads/thread) ----
  async16(aS,                     sm + aDofs);
  async16(aS + (size_t)64 * K,    sm + aDofs + 64 * 64);
  async16(aS + (size_t)128 * K,   sm + aDofs + 128 * 64);
  async16(aS + (size_t)192 * K,   sm + aDofs + 192 * 64);
  async16(bS,                     sm + bDofs);
  async16(bS + (size_t)32 * K,    sm + bDofs + 32 * 64);
  async16(bS + (size_t)128 * K,   sm + bDofs + 128 * 64);
  async16(bS + (size_t)160 * K,   sm + bDofs + 160 * 64);

  f32x4 acc[8][4] = {};
  f16x8 af[4][2], bf[4][2];

  for (int t = 0; t < NT; ++t) {
    const int b = t & 1, nb = b ^ 1;
    const int tn = (t + 1 < NT) ? t + 1 : t;
    const f16* pA = sm + b * 32768;
    const f16* pB = pA + 16384;
    f16* aD = sm + nb * 32768 + aDofs;
    f16* bD = sm + nb * 32768 + bDofs;
    const f16* aSk = aS + tn * 64;
    const f16* bSk = bS + tn * 64;

    __builtin_amdgcn_s_barrier();   // A: t-1 compute closed -> buffer nb free

    async16(aSk,                   aD);
    async16(aSk + (size_t)64 * K,  aD + 64 * 64);
    async16(aSk + (size_t)128 * K, aD + 128 * 64);
    async16(aSk + (size_t)192 * K, aD + 192 * 64);
    async16(bSk,                   bD);
    async16(bSk + (size_t)32 * K,  bD + 32 * 64);
    async16(bSk + (size_t)128 * K, bD + 128 * 64);
    async16(bSk + (size_t)160 * K, bD + 160 * 64);

    asm volatile("s_waitcnt vmcnt(8)" ::: "memory");  // tile t's 8 arrived
    __builtin_amdgcn_s_barrier();   // E: tile t visible

    // ---- phase 1: (i0-3, j0-1) ----
#pragma unroll
    for (int i = 0; i < 4; ++i) {
      const f16* p = pA + (wrow + i * 16 + lm) * 64;
      af[i][0] = *(const f16x8*)(p + x0);
      af[i][1] = *(const f16x8*)(p + x1);
    }
#pragma unroll
    for (int j = 0; j < 2; ++j) {
      const f16* p = pB + (wcol + j * 16 + lm) * 64;
      bf[j][0] = *(const f16x8*)(p + x0);
      bf[j][1] = *(const f16x8*)(p + x1);
    }
    __builtin_amdgcn_s_setprio(1);
#pragma unroll
    for (int i = 0; i < 4; ++i)
#pragma unroll
      for (int j = 0; j < 2; ++j) {
        acc[i][j] = __builtin_amdgcn_mfma_f32_16x16x32_f16(af[i][0], bf[j][0], acc[i][j], 0, 0, 0);
        acc[i][j] = __builtin_amdgcn_mfma_f32_16x16x32_f16(af[i][1], bf[j][1], acc[i][j], 0, 0, 0);
      }
    __builtin_amdgcn_s_setprio(0);
    __builtin_amdgcn_s_barrier();

    // ---- phase 2: (i0-3, j2-3) ----
#pragma unroll
    for (int j = 0; j < 2; ++j) {
      const f16* p = pB + (wcol + 32 + j * 16 + lm) * 64;
      bf[2 + j][0] = *(const f16x8*)(p + x0);
      bf[2 + j][1] = *(const f16x8*)(p + x1);
    }
    __builtin_amdgcn_s_setprio(1);
#pragma unroll
    for (int i = 0; i < 4; ++i)
#pragma unroll
      for (int j = 2; j < 4; ++j) {
        acc[i][j] = __builtin_amdgcn_mfma_f32_16x16x32_f16(af[i][0], bf[j][0], acc[i][j], 0, 0, 0);
        acc[i][j] = __builtin_amdgcn_mfma_f32_16x16x32_f16(af[i][1], bf[j][1], acc[i][j], 0, 0, 0);
      }
    __builtin_amdgcn_s_setprio(0);
    __builtin_amdgcn_s_barrier();

    // ---- phase 3: (i4-7, j0-1) ----
#pragma unroll
    for (int i = 0; i < 4; ++i) {
      const f16* p = pA + (wrow + 64 + i * 16 + lm) * 64;
      af[i][0] = *(const f16x8*)(p + x0);
      af[i][1] = *(const f16x8*)(p + x1);
    }
    __builtin_amdgcn_s_setprio(1);
#pragma unroll
    for (int i = 0; i < 4; ++i)
#pragma unroll
      for (int j = 0; j < 2; ++j) {
        acc[4 + i][j] = __builtin_amdgcn_mfma_f32_16x16x32_f16(af[i][0], bf[j][0], acc[4 + i][j], 0, 0, 0);
        acc[4 + i][j] = __builtin_amdgcn_mfma_f32_16x16x32_f16(af[i][1], bf[j][1], acc[4 + i][j], 0, 0, 0);
      }
    __builtin_amdgcn_s_setprio(0);
    __builtin_amdgcn_s_barrier();

    // ---- phase 4: (i4-7, j2-3) ----
    __builtin_amdgcn_s_setprio(1);
#pragma unroll
    for (int i = 0; i < 4; ++i)
#pragma unroll
      for (int j = 2; j < 4; ++j) {
        acc[4 + i][j] = __builtin_amdgcn_mfma_f32_16x16x32_f16(af[i][0], bf[j][0], acc[4 + i][j], 0, 0, 0);
        acc[4 + i][j] = __builtin_amdgcn_mfma_f32_16x16x32_f16(af[i][1], bf[j][1], acc[4 + i][j], 0, 0, 0);
      }
    __builtin_amdgcn_s_setprio(0);
  }
  asm volatile("s_waitcnt vmcnt(0)" ::: "memory");

  // ---- fused epilogue ----
  const int sec = be >> 2;   // 0=q, 1=k, 2=v
  if (sec < 2) {
    f16* dst = (sec == 0) ? Qp : Kp;
    const float scl = (sec == 0) ? 0.125f : 1.0f;   // DH^-0.5 folded into Q
#pragma unroll
    for (int ii = 0; ii < 8; ++ii) {
      size_t mrow = m0 + wrow + (ii >> 2) * 64 + (ii & 3) * 16 + q * 4;
#pragma unroll
      for (int j = 0; j < 4; ++j) {
        int hd = (int)((e0 + wcol + j * 16 + lm) & 1023);
        int h = hd >> 6, d = hd & 63;
#pragma unroll
        for (int g = 0; g < 4; ++g) {
          size_t tok = mrow + g;
          int n = (int)(tok & 1023);
          size_t bh = (tok >> 10) * 16 + h;
          float sp = softplusf(acc[ii][j][g]) * scl;
          float4 T = trig[n * 64 + d];
          float c = (sec == 0) ? T.x : T.z;
          float s = (sec == 0) ? T.y : T.w;
          f16x2 o = { (f16)(sp * c), (f16)(sp * s) };
          *(f16x2*)(dst + (bh * (size_t)Nn + n) * 128 + 2 * d) = o;
        }
      }
    }
  } else {
#pragma unroll
    for (int ii = 0; ii < 8; ++ii) {
      size_t mrow = m0 + wrow + (ii >> 2) * 64 + (ii & 3) * 16 + q * 4;
#pragma unroll
      for (int j = 0; j < 4; ++j) {
        int hd = (int)((e0 + wcol + j * 16 + lm) & 1023);
#pragma unroll
        for (int g = 0; g < 4; ++g)
          Vn[(mrow + g) * 1024 + hd] = (f16)acc[ii][j][g];
      }
    }
  }
}

// ---------------- V transpose: Vn [token][h*64+d] -> Vt [bh][d][n] ----------------
__global__ __launch_bounds__(256) void vtrans_kernel(const f16* __restrict__ Vn,
                                                     f16* __restrict__ Vt) {
  __shared__ f16 vt[64 * 66];
  int tid = threadIdx.x;
  int bx = blockIdx.x;
  int nt = bx & 15, bh = bx >> 4;
  int b = bh >> 4, h = bh & 15;
  size_t tok0 = (size_t)b * Nn + nt * 64;
  int n0 = nt * 64;
#pragma unroll
  for (int i = 0; i < 8; ++i) {
    int e2 = tid + i * 256;
    int nl = e2 >> 5, dp = (e2 & 31) * 2;
    f16x2 v2 = *(const f16x2*)(Vn + (tok0 + nl) * 1024 + h * 64 + dp);
    vt[dp * 66 + nl]       = v2[0];
    vt[(dp + 1) * 66 + nl] = v2[1];
  }
  __syncthreads();
#pragma unroll
  for (int i = 0; i < 16; ++i) {
    int e = tid + i * 256;
    int d = e >> 6, nl = e & 63;
    Vt[((size_t)bh * 64 + d) * Nn + n0 + nl] = vt[d * 66 + nl];
  }
}

// ---------------- flash attention v5 (round-1 exact, 76.6 us) ----------------
// 256 threads / 4 waves / 128 q-rows / 1024 blocks / 3 blocks/CU, __syncthreads
// pipeline.  Rounds 2-7 showed every modification regresses (8-wave shape,
// counted vmcnt, exp2/defer-max/cvt_pk, setprio) — this is the local optimum.
constexpr int VK0 = 0;       // halfs
constexpr int VK1 = 8192;
constexpr int VV0 = 16384;   // 80*64 = 5120 halfs per buffer
constexpr int VV1 = 21504;
constexpr int VEND = 26624;

__global__ __launch_bounds__(256, 3) void attn_kernel(const f16* __restrict__ Qp,
                                                      const f16* __restrict__ Kp,
                                                      const f16* __restrict__ Vt,
                                                      f16* __restrict__ attout) {
  __shared__ f16 smem[VEND];  // 52 KB

  int tid = threadIdx.x, lane = tid & 63;
  int wv = __builtin_amdgcn_readfirstlane(tid >> 6);  // 0..3
  int lm = lane & 15, q = lane >> 4;
  int bx = blockIdx.x;
  int bh = (bx & 7) | ((bx >> 6) << 3);  // XCD swizzle: same head -> same bx%8
  int qt = (bx >> 3) & 7;                // 8 q-tiles of 128 rows
  const f16* Kbase = Kp + (size_t)bh * Nn * 128;
  const f16* Vbase = Vt + (size_t)bh * 64 * Nn;

  // ---- init V rows 64..79 (row 64 = ones, rest 0) in BOTH buffers, once ----
  {
    int idx = tid * 4;                 // 0..1020
    f16 val = (idx < 64) ? (f16)1.0f : (f16)0.0f;  // idx>>6==0 -> row 64
    f16x4 v4 = {val, val, val, val};
    *(f16x4*)(smem + VV0 + 64 * 64 + idx) = v4;
    *(f16x4*)(smem + VV1 + 64 * 64 + idx) = v4;
  }

  // ---- prologue: DMA K/V tile 0 ----
#pragma unroll
  for (int i = 0; i < 4; ++i) {
    int s = i * 256 + tid;
    int r = s >> 4, c = s & 15;
    int g = c ^ (r & 15);
    async16(Kbase + (size_t)r * 128 + g * 8, smem + VK0 + (i * 256 + wv * 64) * 8);
  }
#pragma unroll
  for (int i = 0; i < 2; ++i) {
    int s = i * 256 + tid;
    int r = s >> 3, c = s & 7;
    int g = c ^ (r & 7);
    async16(Vbase + (size_t)r * Nn + g * 8, smem + VV0 + (i * 256 + wv * 64) * 8);
  }

  // ---- Q frags: 32 rows/wave = 2 groups of 16 (B operand of S^T) ----
  f16x8 qf[2][4];
  {
    const f16* Qb = Qp + ((size_t)bh * Nn + qt * 128 + wv * 32) * 128;
#pragma unroll
    for (int grp = 0; grp < 2; ++grp)
#pragma unroll
      for (int ks = 0; ks < 4; ++ks)
        qf[grp][ks] = *(const f16x8*)(Qb + (size_t)(grp * 16 + lm) * 128 + ks * 32 + q * 8);
  }

  f32x4 O[2][5] = {};   // O^T per group; [.][4] row 0 = softmax denominator
  float mrow[2] = {-INFINITY, -INFINITY};

  for (int kt = 0; kt < 16; ++kt) {
    __syncthreads();  // tile kt ready (its DMA was issued a full compute-phase ago)

    if (kt < 15) {
      f16* nK = smem + ((kt & 1) ? VK0 : VK1);
      f16* nV = smem + ((kt & 1) ? VV0 : VV1);
#pragma unroll
      for (int i = 0; i < 4; ++i) {
        int s = i * 256 + tid;
        int r = s >> 4, c = s & 15;
        int g = c ^ (r & 15);
        async16(Kbase + (size_t)((kt + 1) * 64 + r) * 128 + g * 8, nK + (i * 256 + wv * 64) * 8);
      }
#pragma unroll
      for (int i = 0; i < 2; ++i) {
        int s = i * 256 + tid;
        int r = s >> 3, c = s & 7;
        int g = c ^ (r & 7);
        async16(Vbase + (size_t)r * Nn + (kt + 1) * 64 + g * 8, nV + (i * 256 + wv * 64) * 8);
      }
    }
    const f16* sK = smem + ((kt & 1) ? VK1 : VK0);
    const f16* sV = smem + ((kt & 1) ? VV1 : VV0);

    // ---- S^T = Kp * Qp^T (64 keys x 32 q-rows); kf loaded once per nt ----
    f32x4 S[2][4] = {};
#pragma unroll
    for (int nt = 0; nt < 4; ++nt) {
      f16x8 kf[4];
#pragma unroll
      for (int ks = 0; ks < 4; ++ks)
        kf[ks] = *(const f16x8*)(sK + (nt * 16 + lm) * 128 + (((ks * 4 + q) ^ lm) * 8));
#pragma unroll
      for (int ks = 0; ks < 4; ++ks) {
        S[0][nt] = __builtin_amdgcn_mfma_f32_16x16x32_f16(kf[ks], qf[0][ks], S[0][nt], 0, 0, 0);
        S[1][nt] = __builtin_amdgcn_mfma_f32_16x16x32_f16(kf[ks], qf[1][ks], S[1][nt], 0, 0, 0);
      }
    }

    // ---- online softmax per group (no rowsum: folded into PV ones-row) ----
    f16x4 pf[2][4];
#pragma unroll
    for (int grp = 0; grp < 2; ++grp) {
      float mx = -INFINITY;
#pragma unroll
      for (int nt = 0; nt < 4; ++nt)
#pragma unroll
        for (int g = 0; g < 4; ++g) mx = fmaxf(mx, S[grp][nt][g]);
      mx = fmaxf(mx, __shfl_xor(mx, 16, 64));
      mx = fmaxf(mx, __shfl_xor(mx, 32, 64));
      float mn = fmaxf(mrow[grp], mx);
      float alpha = __expf(mrow[grp] - mn);
      mrow[grp] = mn;
#pragma unroll
      for (int nt = 0; nt < 4; ++nt)
#pragma unroll
        for (int g = 0; g < 4; ++g)
          pf[grp][nt][g] = (f16)__expf(S[grp][nt][g] - mn);
#pragma unroll
      for (int nto = 0; nto < 5; ++nto)
#pragma unroll
        for (int g = 0; g < 4; ++g) O[grp][nto][g] *= alpha;
    }

    // ---- O^T += V^T * P^T ; vf loaded once per (nto,nt), reused by both groups ----
#pragma unroll
    for (int nto = 0; nto < 5; ++nto) {
      int r = nto * 16 + lm;
#pragma unroll
      for (int nt = 0; nt < 4; ++nt) {
        int c16 = (nt * 2 + (q >> 1)) ^ (r & 7);
        f16x4 vf = *(const f16x4*)(sV + r * 64 + c16 * 8 + (q & 1) * 4);
        O[0][nto] = __builtin_amdgcn_mfma_f32_16x16x16f16(vf, pf[0][nt], O[0][nto], 0, 0, 0);
        O[1][nto] = __builtin_amdgcn_mfma_f32_16x16x16f16(vf, pf[1][nt], O[1][nto], 0, 0, 0);
      }
    }
  }

  // ---- epilogue: l = O[grp][4][0] (d-row 64, lives in q==0 lanes), broadcast ----
  int b = bh >> 4, h = bh & 15;
#pragma unroll
  for (int grp = 0; grp < 2; ++grp) {
    float l = __shfl(O[grp][4][0], lm, 64);  // source lane lm (q==0) holds the rowsum
    float inv = 1.f / l;
    size_t token = (size_t)b * Nn + qt * 128 + wv * 32 + grp * 16 + lm;
#pragma unroll
    for (int nto = 0; nto < 4; ++nto) {
      f16x4 o4;
#pragma unroll
      for (int g = 0; g < 4; ++g) o4[g] = (f16)(O[grp][nto][g] * inv);
      *(f16x4*)(attout + token * (size_t)(Hh * DH) + h * 64 + nto * 16 + q * 4) = o4;
    }
  }
}

// ---------------- launch ----------------
extern "C" void kernel_launch(void* const* d_in, const int* in_sizes, int n_in,
                              void* d_out, int out_size, void* d_ws, size_t ws_size,
                              hipStream_t stream) {
  const float* x     = (const float*)d_in[0];
  const float* freqs = (const float*)d_in[1];
  const float* fbias = (const float*)d_in[2];
  const float* gamma = (const float*)d_in[3];
  const float* beta  = (const float*)d_in[4];
  const float* w_qk  = (const float*)d_in[5];
  const float* w_v   = (const float*)d_in[6];
  const float* w_out = (const float*)d_in[7];
  const float* b_out = (const float*)d_in[8];
  float* out = (float*)d_out;

  const size_t T = (size_t)Bb * Nn;  // 8192 tokens
  f16* WqkvT = (f16*)d_ws;                        // [3072][1024]
  f16* WoutT = WqkvT + (size_t)EQKV * DIM;        // [1024][1024]
  float4* trig = (float4*)(WoutT + (size_t)DIM * DIM);   // [1024*64] float4 (1 MB)
  f16* Xn    = (f16*)(trig + (size_t)Nn * DH);    // [8192][1024]
  f16* Vn    = Xn + T * DIM;                      // [8192][1024]
  f16* AttO  = Vn + T * DIM;                      // [8192][1024]
  f16* Qp    = AttO + T * DIM;                    // [128][1024][128]
  f16* Kp    = Qp + (size_t)128 * Nn * 128;       // [128][1024][128]
  f16* Vt    = Kp + (size_t)128 * Nn * 128;       // [128][64][1024]

  transpose_cvt3<<<dim3(64, 32, 3), 256, 0, stream>>>(w_qk, w_v, w_out, WqkvT, WoutT);

  trig_prep<<<(Nn * DH) / 256, 256, 0, stream>>>(freqs, fbias, trig);

  ln_kernel<<<(int)T, 256, 0, stream>>>(x, gamma, beta, Xn);

  // QKV projection + fused polar epilogue (grid 32x12 = 384, %8==0)
  gemm_qkv<<<(int)(T / 256) * (EQKV / 256), 512, 0, stream>>>(
      Xn, WqkvT, Qp, Kp, Vn, trig, (int)T, DIM);

  vtrans_kernel<<<Bb * Hh * (Nn / 64), 256, 0, stream>>>(Vn, Vt);

  // attention: v5 shell — 1024 blocks (128 bh x 8 qt) x 256 threads, 3 blocks/CU
  attn_kernel<<<Bb * Hh * (Nn / 128), 256, 0, stream>>>(Qp, Kp, Vt, AttO);

  gemm_bt<true><<<(int)(T / 128) * (DIM / 128), 256, 0, stream>>>(
      AttO, WoutT, (void*)out, b_out, (int)T, DIM, DIM);
}